// Round 7
// baseline (389.756 us; speedup 1.0000x reference)
//
#include <hip/hip_runtime.h>
#include <hip/hip_bf16.h>
#include <stdint.h>

#define B_    256
#define T_    512
#define N_    256
#define START_ 254
#define STOP_  255
#define GCOLS 16
#define NF    16          // forward denominator blocks
#define ND    32          // total denominator blocks (16 fwd + 16 bwd)
#define LOG2E 1.4426950408889634f
#define LN2   0.6931471805599453f

// d_ws float layout: [0,65536) alphaF, [65536,131072) betaB, [131072,131328) CF, [131328,131584) CB
#define WSB_OFF 65536
#define WCF_OFF 131072
#define WCB_OFF 131328

typedef __attribute__((ext_vector_type(4))) float floatx4;
typedef __attribute__((ext_vector_type(2))) long long llx2;
typedef __attribute__((ext_vector_type(4))) unsigned int uintx4;

__device__ __forceinline__ void lds_barrier() {
    asm volatile("s_waitcnt lgkmcnt(0)\n\ts_barrier" ::: "memory");
}

__device__ __forceinline__ int pk_fp8x4(float a, float b, float c, float d) {  // e4m3
    int r = __builtin_amdgcn_cvt_pk_fp8_f32(a, b, 0, false);
    return __builtin_amdgcn_cvt_pk_fp8_f32(c, d, r, true);
}
__device__ __forceinline__ int pk_bf8x4(float a, float b, float c, float d) {  // e5m2
    int r = __builtin_amdgcn_cvt_pk_bf8_f32(a, b, 0, false);
    return __builtin_amdgcn_cvt_pk_bf8_f32(c, d, r, true);
}
__device__ __forceinline__ long long mk64(int lo, int hi) {
    return ((long long)(unsigned long long)(unsigned)hi << 32) | (unsigned)lo;
}
__device__ __forceinline__ unsigned umax_(unsigned a, unsigned b) { return a > b ? a : b; }

// V layout (per buffer, 4096 B): element (k, col b) at
//   (k>>6)*1024 + ((k>>3)&3)*256 + b*16 + ((k>>5)&1)*8 + (k&7)
// Read: lane l does ds_read_b128 at p*1024 + 16*l -> contiguous 1KB per wave
// per p (zero bank conflicts); low 8B = kt=2p, high 8B = kt=2p+1.
struct DenomShared {
    alignas(16) char  V[2][4096];
    alignas(16) unsigned short mexp[GCOLS * 8];  // per-col max exponents (u16/wave)
    alignas(16) float sbuf[GCOLS * 20];          // per-col sum partials (mask-dead path)
};

// 512 threads = 8 waves; wave w owns rows [32w,32w+32) as 2 M-tiles.
// Lane l: q=l>>4, b=l&15 (batch column). A = E (e4m3, fwd) / E^T (bwd),
// persistent in VGPRs. B = V (e5m2) double-buffered in LDS, lane-contiguous.
// Lag-1 pow2 normalization: produce writes the fully-reduced per-(wave,col)
// max *exponent* as u16 (16B/col); consume is ONE ds_read_b128 + packed max.
// Sum partials are only read under __any(mask==0) (never on this input).
template<bool ISF>
__device__ __forceinline__ void denom_path(
    DenomShared& sh, const float* __restrict__ inputs,
    const float* __restrict__ trans, const int* __restrict__ mask,
    float* __restrict__ ws, int blkLocal)
{
    const int tid = threadIdx.x;
    const int w = tid >> 6;
    const int l = tid & 63;
    const int q = l >> 4;
    const int b = l & 15;
    const int bg = blkLocal * GCOLS + b;
    const int j0 = 32 * w + 4 * q;          // + 16*mt
    const int S = ISF ? 256 : 255;          // serial steps after init

    auto EIDX = [](int s) { return ISF ? s : (511 - s); };
    auto MIDX = [](int s) { return ISF ? (s - 1) : (511 - s); };

    // write address: state j = 32w+16mt+4q+r (r contiguous), + mt*512
    const int wa0 = ((w >> 1) << 10) + ((q >> 1) << 8) + (b << 4)
                  + ((w & 1) << 3) + ((q & 1) << 2);
    const int rbase = l << 4;               // read base: p*1024 + 16*l

    // ---- persistent A-fragments (e4m3): fwd A=E, bwd A=E^T
    long long afrag[2][8];
    #pragma unroll
    for (int mt = 0; mt < 2; ++mt) {
        const int row = 32 * w + 16 * mt + b;
        #pragma unroll
        for (int kt = 0; kt < 8; ++kt) {
            float e[8];
            if (ISF) {
                const float* p = trans + row * N_ + kt * 32 + q * 8;
                floatx4 t0 = *(const floatx4*)p;
                floatx4 t1 = *(const floatx4*)(p + 4);
                #pragma unroll
                for (int jj = 0; jj < 4; ++jj) {
                    e[jj]     = __builtin_amdgcn_exp2f(t0[jj] * LOG2E);
                    e[jj + 4] = __builtin_amdgcn_exp2f(t1[jj] * LOG2E);
                }
            } else {
                #pragma unroll
                for (int jj = 0; jj < 8; ++jj) {
                    const int k = kt * 32 + q * 8 + jj;
                    e[jj] = __builtin_amdgcn_exp2f(trans[k * N_ + row] * LOG2E);
                }
            }
            afrag[mt][kt] = mk64(pk_fp8x4(e[0], e[1], e[2], e[3]),
                                 pk_fp8x4(e[4], e[5], e[6], e[7]));
        }
    }

    const float* emitp = inputs + (size_t)bg * T_ * N_;
    const int*   maskp = mask + bg * T_;
    float C = 0.f;
    float u[2][4];

    auto produce = [&]() {
        float mx = u[0][0], sm = 0.f;
        #pragma unroll
        for (int mt = 0; mt < 2; ++mt)
            #pragma unroll
            for (int r = 0; r < 4; ++r) { mx = fmaxf(mx, u[mt][r]); sm += u[mt][r]; }
        mx = fmaxf(mx, __shfl_xor(mx, 16, 64));
        mx = fmaxf(mx, __shfl_xor(mx, 32, 64));
        sm += __shfl_xor(sm, 32, 64);
        if (l < 16)
            sh.mexp[b * 8 + w] =
                (unsigned short)(__builtin_bit_cast(uint32_t, mx) >> 23);
        if (l < 32) sh.sbuf[b * 20 + w * 2 + q] = sm;
    };

    // ---- init (s=0): fwd u=exp(trans[:,START]+emit0); bwd u=exp(trans[STOP,:])
    if (ISF) {
        #pragma unroll
        for (int mt = 0; mt < 2; ++mt) {
            floatx4 em = *(const floatx4*)(emitp + j0 + 16 * mt);
            #pragma unroll
            for (int r = 0; r < 4; ++r) {
                const int j = j0 + 16 * mt + r;
                u[mt][r] = __builtin_amdgcn_exp2f((trans[j * N_ + START_] + em[r]) * LOG2E);
            }
        }
    } else {
        #pragma unroll
        for (int mt = 0; mt < 2; ++mt) {
            floatx4 st = *(const floatx4*)(trans + STOP_ * N_ + j0 + 16 * mt);
            #pragma unroll
            for (int r = 0; r < 4; ++r)
                u[mt][r] = __builtin_amdgcn_exp2f(st[r] * LOG2E);
        }
    }
    {
        float xpi[2][4] = {{1.f,1.f,1.f,1.f},{1.f,1.f,1.f,1.f}};
        if (!ISF) {   // bwd V_0 = u * exp(emit(511))
            #pragma unroll
            for (int mt = 0; mt < 2; ++mt) {
                floatx4 e = *(const floatx4*)(emitp + (size_t)511 * N_ + j0 + 16 * mt);
                #pragma unroll
                for (int r = 0; r < 4; ++r)
                    xpi[mt][r] = __builtin_amdgcn_exp2f(e[r] * LOG2E);
            }
        }
        produce();
        #pragma unroll
        for (int mt = 0; mt < 2; ++mt)
            *(int*)(sh.V[0] + wa0 + (mt << 9)) =
                pk_bf8x4(u[mt][0] * xpi[mt][0], u[mt][1] * xpi[mt][1],
                         u[mt][2] * xpi[mt][2], u[mt][3] * xpi[mt][3]);
    }
    // 2-slot emit/mask prefetch
    floatx4 ebuf[2][2];
    float   mrot[2];
    ebuf[0][0] = *(const floatx4*)(emitp + (size_t)EIDX(1) * N_ + j0);
    ebuf[0][1] = *(const floatx4*)(emitp + (size_t)EIDX(1) * N_ + j0 + 16);
    ebuf[1][0] = *(const floatx4*)(emitp + (size_t)EIDX(2) * N_ + j0);
    ebuf[1][1] = *(const floatx4*)(emitp + (size_t)EIDX(2) * N_ + j0 + 16);
    mrot[0] = (float)maskp[MIDX(1)];
    mrot[1] = (float)maskp[MIDX(2)];
    lds_barrier();

    auto body = [&](int s, int pr, int cur) {
        const int sp = (s + 2 <= S) ? s + 2 : S;   // distance-2 prefetch
        floatx4 eC0 = *(const floatx4*)(emitp + (size_t)EIDX(sp) * N_ + j0);
        floatx4 eC1 = *(const floatx4*)(emitp + (size_t)EIDX(sp) * N_ + j0 + 16);
        const float mC = (float)maskp[MIDX(sp)];

        // B fragments: 4 contiguous b128 (zero conflicts)
        const char* vb = sh.V[pr];
        long long bf[8];
        #pragma unroll
        for (int p = 0; p < 4; ++p) {
            llx2 rd = *(const llx2*)(vb + (p << 10) + rbase);
            bf[2 * p]     = rd[0];
            bf[2 * p + 1] = rd[1];
        }

        // consume lag-1 stats: ONE b128 of u16 exponents -> max -> pow2 rescale
        uintx4 me = *(const uintx4*)&sh.mexp[b * 8];
        unsigned hi = umax_(umax_(me[0], me[1]), umax_(me[2], me[3]));
        unsigned lo = umax_(umax_(me[0] << 16, me[1] << 16),
                            umax_(me[2] << 16, me[3] << 16));
        const int eb = (int)(umax_(hi, lo) >> 16);
        const float rs = __builtin_bit_cast(float, (uint32_t)(249 - eb) << 23); // 2^(122-eb)
        const float dCf = (float)(122 - eb);

        // xp for this step; fwd folds the rescale into the exponent
        float xpv[2][4];
        #pragma unroll
        for (int r = 0; r < 4; ++r) {
            if (ISF) {
                xpv[0][r] = __builtin_amdgcn_exp2f(fmaf(ebuf[cur][0][r], LOG2E, dCf));
                xpv[1][r] = __builtin_amdgcn_exp2f(fmaf(ebuf[cur][1][r], LOG2E, dCf));
            } else {
                xpv[0][r] = __builtin_amdgcn_exp2f(ebuf[cur][0][r] * LOG2E);
                xpv[1][r] = __builtin_amdgcn_exp2f(ebuf[cur][1][r] * LOG2E);
            }
        }

        floatx4 a0 = {0.f,0.f,0.f,0.f}, a1 = {0.f,0.f,0.f,0.f};
        floatx4 a2 = {0.f,0.f,0.f,0.f}, a3 = {0.f,0.f,0.f,0.f};
        #pragma unroll
        for (int kt = 0; kt < 4; ++kt) {   // two 4-deep half-chains per M-tile
            a0 = __builtin_amdgcn_mfma_f32_16x16x32_fp8_bf8(afrag[0][kt],     bf[kt],     a0, 0, 0, 0);
            a1 = __builtin_amdgcn_mfma_f32_16x16x32_fp8_bf8(afrag[0][kt + 4], bf[kt + 4], a1, 0, 0, 0);
            a2 = __builtin_amdgcn_mfma_f32_16x16x32_fp8_bf8(afrag[1][kt],     bf[kt],     a2, 0, 0, 0);
            a3 = __builtin_amdgcn_mfma_f32_16x16x32_fp8_bf8(afrag[1][kt + 4], bf[kt + 4], a3, 0, 0, 0);
        }

        const bool live = (mrot[cur] != 0.f);
        // mask-dead fallback: read sum partials only if any lane is dead
        float csv = 0.f;
        if (__any(!live)) {
            const float* sb = &sh.sbuf[b * 20];
            floatx4 s0 = *(const floatx4*)sb,       s1 = *(const floatx4*)(sb + 4);
            floatx4 s2 = *(const floatx4*)(sb + 8), s3 = *(const floatx4*)(sb + 12);
            csv = ((((s0[0] + s0[1]) + (s0[2] + s0[3])) +
                    ((s1[0] + s1[1]) + (s1[2] + s1[3]))) +
                   (((s2[0] + s2[1]) + (s2[2] + s2[3])) +
                    ((s3[0] + s3[1]) + (s3[2] + s3[3])))) * rs;
        }
        #pragma unroll
        for (int r = 0; r < 4; ++r) {
            const float v0 = a0[r] + a1[r], v1 = a2[r] + a3[r];
            if (ISF) {
                u[0][r] = live ? v0 * xpv[0][r] : csv;   // rs folded in xpv
                u[1][r] = live ? v1 * xpv[1][r] : csv;
            } else {
                u[0][r] = live ? v0 * rs : csv;
                u[1][r] = live ? v1 * rs : csv;
            }
        }
        C += (float)(eb - 122);

        produce();
        // write V: fwd V=u ; bwd V=u*xp
        #pragma unroll
        for (int mt = 0; mt < 2; ++mt) {
            *(int*)(sh.V[pr ^ 1] + wa0 + (mt << 9)) = ISF
                ? pk_bf8x4(u[mt][0], u[mt][1], u[mt][2], u[mt][3])
                : pk_bf8x4(u[mt][0] * xpv[mt][0], u[mt][1] * xpv[mt][1],
                           u[mt][2] * xpv[mt][2], u[mt][3] * xpv[mt][3]);
        }
        lds_barrier();
        ebuf[cur][0] = eC0; ebuf[cur][1] = eC1;
        mrot[cur] = mC;
    };

    #pragma unroll 1
    for (int g = 0; g < 127; ++g) {
        body(2 * g + 1, 0, 0);
        body(2 * g + 2, 1, 1);
    }
    if (ISF) { body(255, 0, 0); body(256, 1, 1); }
    else     { body(255, 0, 0); }

    // ---- store partials: u = alpha(256) (fwd) / beta(256) (bwd), scale 2^-C
    float* wsV = ws + (ISF ? 0 : WSB_OFF);
    #pragma unroll
    for (int mt = 0; mt < 2; ++mt) {
        floatx4 vv = {u[mt][0], u[mt][1], u[mt][2], u[mt][3]};
        *(floatx4*)&wsV[(size_t)bg * N_ + j0 + 16 * mt] = vv;
    }
    if (tid < 16) {
        float* wsC = ws + (ISF ? WCF_OFF : WCB_OFF);
        wsC[blkLocal * GCOLS + tid] = C;
    }
}

__global__ __launch_bounds__(512, 2) void crf_main(
    const float* __restrict__ inputs, const float* __restrict__ trans,
    const int* __restrict__ tags, const int* __restrict__ mask,
    float* __restrict__ out, float* __restrict__ ws)
{
    __shared__ DenomShared sh;

    if (blockIdx.x >= ND) {
        // ---------------- numerator: one batch per block ----------------
        float* nred = sh.sbuf;              // [0,8)
        int*   nredi = (int*)(sh.sbuf + 8); // [8,16)
        const int bb = blockIdx.x - ND;
        const int t  = threadIdx.x;            // 0..511
        const int tg = tags[bb * T_ + t];
        const float fm = (float)mask[bb * T_ + t];
        float part = 0.f;
        if (t >= 1)      part += trans[tg * N_ + tags[bb * T_ + t - 1]] * fm;
        if (t <= T_ - 2) part += inputs[((size_t)bb * T_ + t) * N_ + tg] * fm;
        int ms = mask[bb * T_ + t];
        #pragma unroll
        for (int off = 1; off < 64; off <<= 1) {
            part += __shfl_xor(part, off, 64);
            ms   += __shfl_xor(ms, off, 64);
        }
        if ((t & 63) == 0) { nred[t >> 6] = part; nredi[t >> 6] = ms; }
        __syncthreads();
        if (t == 0) {
            float tot = 0.f; int mtot = 0;
            for (int i = 0; i < 8; ++i) { tot += nred[i]; mtot += nredi[i]; }
            tot += trans[tags[bb * T_] * N_ + START_];
            const int last = mtot - 1;
            const int lt = tags[bb * T_ + last];
            tot += trans[STOP_ * N_ + lt]
                 + inputs[((size_t)bb * T_ + (T_ - 1)) * N_ + lt]
                   * (float)mask[bb * T_ + T_ - 1];
            atomicAdd(out, tot);
        }
        return;
    }

    if (blockIdx.x < NF) denom_path<true>(sh, inputs, trans, mask, ws, blockIdx.x);
    else                 denom_path<false>(sh, inputs, trans, mask, ws, blockIdx.x - NF);
}

// denom_b = LN2 * (CF_b + CB_b + log2(sum_j alphaF[b][j] * betaB[b][j]))
__global__ __launch_bounds__(256) void crf_combine(
    const float* __restrict__ ws, float* __restrict__ out)
{
    __shared__ float red[4];
    const int bb = blockIdx.x;
    const int t = threadIdx.x;
    float p = ws[(size_t)bb * N_ + t] * ws[WSB_OFF + (size_t)bb * N_ + t];
    #pragma unroll
    for (int off = 1; off < 64; off <<= 1) p += __shfl_xor(p, off, 64);
    if ((t & 63) == 0) red[t >> 6] = p;
    __syncthreads();
    if (t == 0) {
        const float tot = red[0] + red[1] + red[2] + red[3];
        const float denom = (ws[WCF_OFF + bb] + ws[WCB_OFF + bb]
                             + __builtin_amdgcn_logf(tot)) * LN2;
        atomicAdd(out, -denom);
    }
}

extern "C" void kernel_launch(void* const* d_in, const int* in_sizes, int n_in,
                              void* d_out, int out_size, void* d_ws, size_t ws_size,
                              hipStream_t stream) {
    const float* inputs = (const float*)d_in[0];
    const float* trans  = (const float*)d_in[1];
    const int*   tags   = (const int*)d_in[2];
    const int*   mask   = (const int*)d_in[3];
    float* out = (float*)d_out;
    float* ws  = (float*)d_ws;
    hipMemsetAsync(out, 0, sizeof(float), stream);
    crf_main<<<dim3(ND + B_), dim3(512), 0, stream>>>(inputs, trans, tags, mask, out, ws);
    crf_combine<<<dim3(B_), dim3(256), 0, stream>>>(ws, out);
}

// Round 8
// 344.011 us; speedup vs baseline: 1.1330x; 1.1330x over previous
//
#include <hip/hip_runtime.h>
#include <hip/hip_bf16.h>
#include <stdint.h>

#define B_    256
#define T_    512
#define N_    256
#define START_ 254
#define STOP_  255
#define GCOLS 16
#define NF    16          // forward denominator blocks
#define ND    32          // total denominator blocks (16 fwd + 16 bwd)
#define LOG2E 1.4426950408889634f
#define LN2   0.6931471805599453f

// d_ws float layout: [0,65536) alphaF, [65536,131072) betaB, [131072,131328) CF, [131328,131584) CB
#define WSB_OFF 65536
#define WCF_OFF 131072
#define WCB_OFF 131328

typedef __attribute__((ext_vector_type(4))) float floatx4;
typedef __attribute__((ext_vector_type(4))) unsigned int uintx4;
typedef __attribute__((ext_vector_type(8))) int v8i;

template<bool X> struct BC { static constexpr bool value = X; };

__device__ __forceinline__ void lds_barrier() {
    asm volatile("s_waitcnt lgkmcnt(0)\n\ts_barrier" ::: "memory");
}

__device__ __forceinline__ int pk_fp8x4(float a, float b, float c, float d) {  // e4m3
    int r = __builtin_amdgcn_cvt_pk_fp8_f32(a, b, 0, false);
    return __builtin_amdgcn_cvt_pk_fp8_f32(c, d, r, true);
}
__device__ __forceinline__ int pk_bf8x4(float a, float b, float c, float d) {  // e5m2
    int r = __builtin_amdgcn_cvt_pk_bf8_f32(a, b, 0, false);
    return __builtin_amdgcn_cvt_pk_bf8_f32(c, d, r, true);
}

// V layout (per buffer, 4096 B): element (k, col b), k = state index:
//   c=k>>7, qk=(k>>5)&3, j=k&31, r=j>>4, j'=j&15
//   addr = ((c*2+r)<<10) + (qk<<8) + (b<<4) + j'
// Read (lane l=q*16+b, chunk c): two b128 at (2c)*1024+16l and (2c+1)*1024+16l
// -> contiguous 1KB per wave per page, zero conflicts. Bytes 0..31 = k
// [c*128+q*32, +32) in order == A/B operand byte order of 16x16x128 f8f6f4.
struct DenomShared {
    alignas(16) char  V[2][4096];
    alignas(16) float mbuf[GCOLS * 36];   // per-lane max partials [b][w*4+q], pitch 36
    alignas(16) float sbuf[GCOLS * 20];   // sum partials (slow/mask-dead path only)
    int flag;
};

// 512 threads = 8 waves; wave w owns rows [32w,32w+32) as 2 M-tiles.
// Lane l: q=l>>4, b=l&15 (batch column). A = E (e4m3, fwd) / E^T (bwd),
// persistent in VGPRs as f8f6f4 A-fragments. B = V (e5m2) in LDS, dbuffered.
// MFMA: mfma_scale_f32_16x16x128_f8f6f4, cbsz=0 (A e4m3), blgp=1 (B e5m2),
// scales = 0x7F (e8m0 1.0). Lag-1 pow2 normalization, zero-shuffle produce.
template<bool ISF>
__device__ __forceinline__ void denom_path(
    DenomShared& sh, const float* __restrict__ inputs,
    const float* __restrict__ trans, const int* __restrict__ mask,
    float* __restrict__ ws, int blkLocal)
{
    const int tid = threadIdx.x;
    const int w = tid >> 6;
    const int l = tid & 63;
    const int q = l >> 4;
    const int b = l & 15;
    const int bg = blkLocal * GCOLS + b;
    const int j0 = 32 * w + 4 * q;          // + 16*mt
    const int S = ISF ? 256 : 255;          // serial steps after init
    const int scl = 0x7F7F7F7F;             // e8m0 scale = 1.0

    auto EIDX = [](int s) { return ISF ? s : (511 - s); };
    auto MIDX = [](int s) { return ISF ? (s - 1) : (511 - s); };

    // V write addresses (one b32 per mt): state j = 32w+16mt+4q+rr
    int wa[2];
    #pragma unroll
    for (int mt = 0; mt < 2; ++mt)
        wa[mt] = ((((2 * w + mt) >> 3) * 2 + mt) << 10)
               + ((w & 3) << 8) + (b << 4) + (q << 2);
    const int rbase = l << 4;

    // ---- persistent A-fragments (e4m3): lane holds E[row][c*128+q*32 .. +32)
    v8i afrag[2][2];
    #pragma unroll
    for (int mt = 0; mt < 2; ++mt) {
        const int row = 32 * w + 16 * mt + b;
        #pragma unroll
        for (int c = 0; c < 2; ++c) {
            v8i a;
            #pragma unroll
            for (int g8 = 0; g8 < 8; ++g8) {
                float e[4];
                if (ISF) {
                    floatx4 t = *(const floatx4*)(trans + row * N_ + c * 128 + q * 32 + 4 * g8);
                    #pragma unroll
                    for (int ii = 0; ii < 4; ++ii)
                        e[ii] = __builtin_amdgcn_exp2f(t[ii] * LOG2E);
                } else {
                    #pragma unroll
                    for (int ii = 0; ii < 4; ++ii) {
                        const int k = c * 128 + q * 32 + 4 * g8 + ii;
                        e[ii] = __builtin_amdgcn_exp2f(trans[k * N_ + row] * LOG2E);
                    }
                }
                a[g8] = pk_fp8x4(e[0], e[1], e[2], e[3]);
            }
            afrag[mt][c] = a;
        }
    }

    // ---- mask-dead scan (once): any zero mask in this block's 16 columns?
    {
        const int* mrow = mask + blkLocal * GCOLS * T_;
        bool hd = false;
        #pragma unroll
        for (int i = 0; i < GCOLS * T_ / 512; ++i)
            hd |= (mrow[tid + 512 * i] == 0);
        if (tid == 0) sh.flag = 0;
        __syncthreads();
        if (__any(hd) && l == 0) atomicOr(&sh.flag, 1);
        __syncthreads();
    }
    const bool anyDead = (sh.flag != 0);

    const float* emitp = inputs + (size_t)bg * T_ * N_;
    const int*   maskp = mask + bg * T_;
    float C = 0.f;
    float u[2][4];

    // ---- init (s=0): fwd u=exp(trans[:,START]+emit0); bwd u=exp(trans[STOP,:])
    if (ISF) {
        #pragma unroll
        for (int mt = 0; mt < 2; ++mt) {
            floatx4 em = *(const floatx4*)(emitp + j0 + 16 * mt);
            #pragma unroll
            for (int r = 0; r < 4; ++r) {
                const int j = j0 + 16 * mt + r;
                u[mt][r] = __builtin_amdgcn_exp2f((trans[j * N_ + START_] + em[r]) * LOG2E);
            }
        }
    } else {
        #pragma unroll
        for (int mt = 0; mt < 2; ++mt) {
            floatx4 st = *(const floatx4*)(trans + STOP_ * N_ + j0 + 16 * mt);
            #pragma unroll
            for (int r = 0; r < 4; ++r)
                u[mt][r] = __builtin_amdgcn_exp2f(st[r] * LOG2E);
        }
    }
    {   // init produce (both formats) + V0 write
        float mx = u[0][0], sm = 0.f;
        #pragma unroll
        for (int mt = 0; mt < 2; ++mt)
            #pragma unroll
            for (int r = 0; r < 4; ++r) { mx = fmaxf(mx, u[mt][r]); sm += u[mt][r]; }
        sh.mbuf[b * 36 + w * 4 + q] = mx;
        sm += __shfl_xor(sm, 32, 64);
        if (l < 32) sh.sbuf[b * 20 + w * 2 + q] = sm;

        float xpi[2][4] = {{1.f,1.f,1.f,1.f},{1.f,1.f,1.f,1.f}};
        if (!ISF) {   // bwd V_0 = u * exp(emit(511))
            #pragma unroll
            for (int mt = 0; mt < 2; ++mt) {
                floatx4 e = *(const floatx4*)(emitp + (size_t)511 * N_ + j0 + 16 * mt);
                #pragma unroll
                for (int r = 0; r < 4; ++r)
                    xpi[mt][r] = __builtin_amdgcn_exp2f(e[r] * LOG2E);
            }
        }
        #pragma unroll
        for (int mt = 0; mt < 2; ++mt)
            *(int*)(sh.V[0] + wa[mt]) =
                pk_bf8x4(u[mt][0] * xpi[mt][0], u[mt][1] * xpi[mt][1],
                         u[mt][2] * xpi[mt][2], u[mt][3] * xpi[mt][3]);
    }

    auto run = [&](auto fastc) {
        constexpr bool FAST = decltype(fastc)::value;
        floatx4 ebuf[2][2];
        float   mrot[2] = {1.f, 1.f};
        ebuf[0][0] = *(const floatx4*)(emitp + (size_t)EIDX(1) * N_ + j0);
        ebuf[0][1] = *(const floatx4*)(emitp + (size_t)EIDX(1) * N_ + j0 + 16);
        ebuf[1][0] = *(const floatx4*)(emitp + (size_t)EIDX(2) * N_ + j0);
        ebuf[1][1] = *(const floatx4*)(emitp + (size_t)EIDX(2) * N_ + j0 + 16);
        if (!FAST) {
            mrot[0] = (float)maskp[MIDX(1)];
            mrot[1] = (float)maskp[MIDX(2)];
        }
        lds_barrier();

        auto body = [&](int s, int pr, int cur) {
            const int sp = (s + 2 <= S) ? s + 2 : S;   // distance-2 prefetch
            floatx4 eC0 = *(const floatx4*)(emitp + (size_t)EIDX(sp) * N_ + j0);
            floatx4 eC1 = *(const floatx4*)(emitp + (size_t)EIDX(sp) * N_ + j0 + 16);
            float mC = 1.f;
            if (!FAST) mC = (float)maskp[MIDX(sp)];

            // B fragments: 4 contiguous b128 (zero conflicts)
            const char* vb = sh.V[pr];
            v8i bfrag[2];
            #pragma unroll
            for (int c = 0; c < 2; ++c) {
                uintx4 r0 = *(const uintx4*)(vb + (c << 11) + rbase);
                uintx4 r1 = *(const uintx4*)(vb + (c << 11) + 1024 + rbase);
                v8i bf;
                bf[0] = r0[0]; bf[1] = r0[1]; bf[2] = r0[2]; bf[3] = r0[3];
                bf[4] = r1[0]; bf[5] = r1[1]; bf[6] = r1[2]; bf[7] = r1[3];
                bfrag[c] = bf;
            }

            // consume lag-1 stats: 8 b128 (hidden under MFMA wait) -> max -> pow2
            const float* mb = &sh.mbuf[b * 36];
            float cmax;
            {
                floatx4 mm[8];
                #pragma unroll
                for (int i = 0; i < 8; ++i) mm[i] = *(const floatx4*)(mb + 4 * i);
                floatx4 mv = mm[0];
                #pragma unroll
                for (int i = 1; i < 8; ++i)
                    #pragma unroll
                    for (int r = 0; r < 4; ++r) mv[r] = fmaxf(mv[r], mm[i][r]);
                cmax = fmaxf(fmaxf(mv[0], mv[1]), fmaxf(mv[2], mv[3]));
            }
            const uint32_t cb = __builtin_bit_cast(uint32_t, cmax);
            const int eb = (int)((cb >> 23) & 0xFFu);
            const float rs = __builtin_bit_cast(float, (uint32_t)(249 - eb) << 23); // 2^(122-eb)
            const float dCf = (float)(122 - eb);

            // xp for this step; fwd folds the rescale into the exponent
            float xpv[2][4];
            #pragma unroll
            for (int r = 0; r < 4; ++r) {
                if (ISF) {
                    xpv[0][r] = __builtin_amdgcn_exp2f(fmaf(ebuf[cur][0][r], LOG2E, dCf));
                    xpv[1][r] = __builtin_amdgcn_exp2f(fmaf(ebuf[cur][1][r], LOG2E, dCf));
                } else {
                    xpv[0][r] = __builtin_amdgcn_exp2f(ebuf[cur][0][r] * LOG2E);
                    xpv[1][r] = __builtin_amdgcn_exp2f(ebuf[cur][1][r] * LOG2E);
                }
            }

            floatx4 a0 = {0.f,0.f,0.f,0.f}, a1 = {0.f,0.f,0.f,0.f};
            a0 = __builtin_amdgcn_mfma_scale_f32_16x16x128_f8f6f4(
                     afrag[0][0], bfrag[0], a0, 0, 1, 0, scl, 0, scl);
            a1 = __builtin_amdgcn_mfma_scale_f32_16x16x128_f8f6f4(
                     afrag[1][0], bfrag[0], a1, 0, 1, 0, scl, 0, scl);
            a0 = __builtin_amdgcn_mfma_scale_f32_16x16x128_f8f6f4(
                     afrag[0][1], bfrag[1], a0, 0, 1, 0, scl, 0, scl);
            a1 = __builtin_amdgcn_mfma_scale_f32_16x16x128_f8f6f4(
                     afrag[1][1], bfrag[1], a1, 0, 1, 0, scl, 0, scl);

            if (FAST) {
                #pragma unroll
                for (int r = 0; r < 4; ++r) {
                    if (ISF) {
                        u[0][r] = a0[r] * xpv[0][r];   // rs folded in xpv
                        u[1][r] = a1[r] * xpv[1][r];
                    } else {
                        u[0][r] = a0[r] * rs;
                        u[1][r] = a1[r] * rs;
                    }
                }
            } else {
                const bool live = (mrot[cur] != 0.f);
                float csv = 0.f;
                if (__any(!live)) {
                    const float* sb = &sh.sbuf[b * 20];
                    floatx4 s0 = *(const floatx4*)sb,       s1 = *(const floatx4*)(sb + 4);
                    floatx4 s2 = *(const floatx4*)(sb + 8), s3 = *(const floatx4*)(sb + 12);
                    csv = ((((s0[0] + s0[1]) + (s0[2] + s0[3])) +
                            ((s1[0] + s1[1]) + (s1[2] + s1[3]))) +
                           (((s2[0] + s2[1]) + (s2[2] + s2[3])) +
                            ((s3[0] + s3[1]) + (s3[2] + s3[3])))) * rs;
                }
                #pragma unroll
                for (int r = 0; r < 4; ++r) {
                    if (ISF) {
                        u[0][r] = live ? a0[r] * xpv[0][r] : csv;
                        u[1][r] = live ? a1[r] * xpv[1][r] : csv;
                    } else {
                        u[0][r] = live ? a0[r] * rs : csv;
                        u[1][r] = live ? a1[r] * rs : csv;
                    }
                }
            }
            C += (float)(eb - 122);

            // produce: zero cross-lane ops before the barrier
            {
                float mx = fmaxf(fmaxf(fmaxf(u[0][0], u[0][1]), fmaxf(u[0][2], u[0][3])),
                                 fmaxf(fmaxf(u[1][0], u[1][1]), fmaxf(u[1][2], u[1][3])));
                sh.mbuf[b * 36 + w * 4 + q] = mx;
                if (!FAST) {
                    float sm = ((u[0][0] + u[0][1]) + (u[0][2] + u[0][3]))
                             + ((u[1][0] + u[1][1]) + (u[1][2] + u[1][3]));
                    sm += __shfl_xor(sm, 32, 64);
                    if (l < 32) sh.sbuf[b * 20 + w * 2 + q] = sm;
                }
            }
            // write V: fwd V=u ; bwd V=u*xp
            #pragma unroll
            for (int mt = 0; mt < 2; ++mt) {
                *(int*)(sh.V[pr ^ 1] + wa[mt]) = ISF
                    ? pk_bf8x4(u[mt][0], u[mt][1], u[mt][2], u[mt][3])
                    : pk_bf8x4(u[mt][0] * xpv[mt][0], u[mt][1] * xpv[mt][1],
                               u[mt][2] * xpv[mt][2], u[mt][3] * xpv[mt][3]);
            }
            lds_barrier();
            ebuf[cur][0] = eC0; ebuf[cur][1] = eC1;
            if (!FAST) mrot[cur] = mC;
        };

        #pragma unroll 1
        for (int g = 0; g < 127; ++g) {
            body(2 * g + 1, 0, 0);
            body(2 * g + 2, 1, 1);
        }
        if (ISF) { body(255, 0, 0); body(256, 1, 1); }
        else     { body(255, 0, 0); }
    };

    if (anyDead) run(BC<false>{});
    else         run(BC<true>{});

    // ---- store partials: u = alpha(256) (fwd) / beta(256) (bwd), scale 2^-C
    float* wsV = ws + (ISF ? 0 : WSB_OFF);
    #pragma unroll
    for (int mt = 0; mt < 2; ++mt) {
        floatx4 vv = {u[mt][0], u[mt][1], u[mt][2], u[mt][3]};
        *(floatx4*)&wsV[(size_t)bg * N_ + j0 + 16 * mt] = vv;
    }
    if (tid < 16) {
        float* wsC = ws + (ISF ? WCF_OFF : WCB_OFF);
        wsC[blkLocal * GCOLS + tid] = C;
    }
}

__global__ __launch_bounds__(512, 2) void crf_main(
    const float* __restrict__ inputs, const float* __restrict__ trans,
    const int* __restrict__ tags, const int* __restrict__ mask,
    float* __restrict__ out, float* __restrict__ ws)
{
    __shared__ DenomShared sh;

    if (blockIdx.x >= ND) {
        // ---------------- numerator: one batch per block ----------------
        float* nred = sh.sbuf;              // [0,8)
        int*   nredi = (int*)(sh.sbuf + 8); // [8,16)
        const int bb = blockIdx.x - ND;
        const int t  = threadIdx.x;            // 0..511
        const int tg = tags[bb * T_ + t];
        const float fm = (float)mask[bb * T_ + t];
        float part = 0.f;
        if (t >= 1)      part += trans[tg * N_ + tags[bb * T_ + t - 1]] * fm;
        if (t <= T_ - 2) part += inputs[((size_t)bb * T_ + t) * N_ + tg] * fm;
        int ms = mask[bb * T_ + t];
        #pragma unroll
        for (int off = 1; off < 64; off <<= 1) {
            part += __shfl_xor(part, off, 64);
            ms   += __shfl_xor(ms, off, 64);
        }
        if ((t & 63) == 0) { nred[t >> 6] = part; nredi[t >> 6] = ms; }
        __syncthreads();
        if (t == 0) {
            float tot = 0.f; int mtot = 0;
            for (int i = 0; i < 8; ++i) { tot += nred[i]; mtot += nredi[i]; }
            tot += trans[tags[bb * T_] * N_ + START_];
            const int last = mtot - 1;
            const int lt = tags[bb * T_ + last];
            tot += trans[STOP_ * N_ + lt]
                 + inputs[((size_t)bb * T_ + (T_ - 1)) * N_ + lt]
                   * (float)mask[bb * T_ + T_ - 1];
            atomicAdd(out, tot);
        }
        return;
    }

    if (blockIdx.x < NF) denom_path<true>(sh, inputs, trans, mask, ws, blockIdx.x);
    else                 denom_path<false>(sh, inputs, trans, mask, ws, blockIdx.x - NF);
}

// denom_b = LN2 * (CF_b + CB_b + log2(sum_j alphaF[b][j] * betaB[b][j]))
__global__ __launch_bounds__(256) void crf_combine(
    const float* __restrict__ ws, float* __restrict__ out)
{
    __shared__ float red[4];
    const int bb = blockIdx.x;
    const int t = threadIdx.x;
    float p = ws[(size_t)bb * N_ + t] * ws[WSB_OFF + (size_t)bb * N_ + t];
    #pragma unroll
    for (int off = 1; off < 64; off <<= 1) p += __shfl_xor(p, off, 64);
    if ((t & 63) == 0) red[t >> 6] = p;
    __syncthreads();
    if (t == 0) {
        const float tot = red[0] + red[1] + red[2] + red[3];
        const float denom = (ws[WCF_OFF + bb] + ws[WCB_OFF + bb]
                             + __builtin_amdgcn_logf(tot)) * LN2;
        atomicAdd(out, -denom);
    }
}

extern "C" void kernel_launch(void* const* d_in, const int* in_sizes, int n_in,
                              void* d_out, int out_size, void* d_ws, size_t ws_size,
                              hipStream_t stream) {
    const float* inputs = (const float*)d_in[0];
    const float* trans  = (const float*)d_in[1];
    const int*   tags   = (const int*)d_in[2];
    const int*   mask   = (const int*)d_in[3];
    float* out = (float*)d_out;
    float* ws  = (float*)d_ws;
    hipMemsetAsync(out, 0, sizeof(float), stream);
    crf_main<<<dim3(ND + B_), dim3(512), 0, stream>>>(inputs, trans, tags, mask, out, ws);
    crf_combine<<<dim3(B_), dim3(256), 0, stream>>>(ws, out);
}